// Round 1
// baseline (92.518 us; speedup 1.0000x reference)
//
#include <hip/hip_runtime.h>
#include <math.h>

#define D 40
#define NN 1024
#define BB 2

// Branch-free erf, Abramowitz-Stegun 7.1.26, |err| <= 1.5e-7
__device__ __forceinline__ float erf_fast(float x) {
    float ax = fabsf(x);
    float t = __builtin_amdgcn_rcpf(fmaf(0.3275911f, ax, 1.0f));
    float y = t * (0.254829592f + t * (-0.284496736f + t * (1.421413741f +
              t * (-1.453152027f + t * 1.061405429f))));
    float r = 1.0f - y * __expf(-x * x);
    return copysignf(r, x);
}

__device__ __forceinline__ float gelu_exact(float a) {
    return 0.5f * a * (1.0f + erf_fast(a * 0.70710678118654752f));
}

// ai = x @ W1[:D] + b1, aj = x @ W1[D:]
__global__ __launch_bounds__(64) void precompute_kernel(
    const float* __restrict__ x, const float* __restrict__ W1,
    const float* __restrict__ b1, float* __restrict__ ai, float* __restrict__ aj) {
    int r = blockIdx.x;   // 0..B*N-1
    int t = threadIdx.x;  // 64
    __shared__ float xr[D];
    if (t < D) xr[t] = x[(size_t)r * D + t];
    __syncthreads();
    if (t < D) {
        float s1 = b1[t];
        float s2 = 0.0f;
#pragma unroll
        for (int k = 0; k < D; ++k) {
            float xv = xr[k];
            s1 = fmaf(xv, W1[k * D + t], s1);
            s2 = fmaf(xv, W1[(D + k) * D + t], s2);
        }
        ai[(size_t)r * D + t] = s1;
        aj[(size_t)r * D + t] = s2;
    }
}

__global__ __launch_bounds__(256) void pair_kernel(
    const float* __restrict__ ai_g, const float* __restrict__ aj_g,
    const float* __restrict__ W2, const float* __restrict__ b2,
    float* __restrict__ out) {
    __shared__ float lds_a[256 * 41];  // staged aj rows (stride 41), reused as reduction buf
    __shared__ float sm[256];

    const int t = threadIdx.x;
    const int bid = blockIdx.x;
    const int b = bid & 1;
    const int i = NN - 1 - (bid >> 1);  // big rows dispatched first

    const float* __restrict__ ai_row = ai_g + ((size_t)b * NN + i) * D;  // uniform

    float m = 0.0f, l = 0.0f;
    float o[D];
#pragma unroll
    for (int d = 0; d < D; ++d) o[d] = 0.0f;

    const int nwin = (i + 256) >> 8;  // ceil((i+1)/256)
    for (int w = 0; w < nwin; ++w) {
        const int jbase = w << 8;
        // ---- stage 256 aj rows (source row clamped to i -> always finite) ----
#pragma unroll
        for (int s = 0; s < 10; ++s) {
            int idx4 = t + (s << 8);   // 0..2559
            int e0 = idx4 << 2;        // element index 0..10236
            int row = e0 / 40;
            int col = e0 - row * 40;   // multiple of 4
            int jsrc = jbase + row;
            if (jsrc > i) jsrc = i;
            const float4 v = *reinterpret_cast<const float4*>(
                aj_g + ((size_t)b * NN + jsrc) * D + col);
            float* dst = lds_a + row * 41 + col;
            dst[0] = v.x; dst[1] = v.y; dst[2] = v.z; dst[3] = v.w;
        }
        __syncthreads();

        const int j = jbase + t;
        const bool valid = (j <= i);
        const float* arow = lds_a + t * 41;

        float p[D];
#pragma unroll
        for (int d = 0; d < D; ++d) p[d] = b2[d];
#pragma unroll 4
        for (int k = 0; k < D; ++k) {
            float a = ai_row[k] + arow[k];
            float hk = gelu_exact(a);
#pragma unroll
            for (int d = 0; d < D; ++d) p[d] = fmaf(hk, W2[k * D + d], p[d]);
        }
        float sq = 0.0f;
#pragma unroll
        for (int d = 0; d < D; ++d) sq = fmaf(p[d], p[d], sq);
        float s = sqrtf(sq);

        // online softmax update (branch-free, masked lanes contribute 0)
        float sv = valid ? s : 0.0f;
        float mn = fmaxf(m, sv);
        float scale = __expf(m - mn);        // == 1.0 exactly when mn == m
        float wgt = valid ? __expf(s - mn) : 0.0f;
        l = fmaf(l, scale, wgt);
#pragma unroll
        for (int d = 0; d < D; ++d) o[d] = fmaf(o[d], scale, wgt * p[d]);
        m = mn;
        __syncthreads();
    }

    // ---- merge 256 online-softmax states ----
    sm[t] = m;
    __syncthreads();
    for (int off = 128; off > 0; off >>= 1) {
        if (t < off) sm[t] = fmaxf(sm[t], sm[t + off]);
        __syncthreads();
    }
    const float M = sm[0];
    __syncthreads();
    const float c = __expf(m - M);
    float* row = lds_a + t * 41;
#pragma unroll
    for (int d = 0; d < D; ++d) row[d] = o[d] * c;
    row[D] = l * c;
    __syncthreads();
    for (int off = 128; off > 0; off >>= 1) {
        if (t < off) {
            float* a_ = lds_a + t * 41;
            const float* b_ = lds_a + (t + off) * 41;
#pragma unroll
            for (int d = 0; d <= D; ++d) a_[d] += b_[d];
        }
        __syncthreads();
    }
    if (t < D) {
        out[((size_t)b * NN + i) * D + t] = lds_a[t] / lds_a[D];
    }
}

extern "C" void kernel_launch(void* const* d_in, const int* in_sizes, int n_in,
                              void* d_out, int out_size, void* d_ws, size_t ws_size,
                              hipStream_t stream) {
    const float* x  = (const float*)d_in[0];
    const float* W1 = (const float*)d_in[1];
    const float* b1 = (const float*)d_in[2];
    const float* W2 = (const float*)d_in[3];
    const float* b2 = (const float*)d_in[4];
    float* out = (float*)d_out;

    float* ai = (float*)d_ws;            // B*N*D floats
    float* aj = ai + (size_t)BB * NN * D;

    precompute_kernel<<<BB * NN, 64, 0, stream>>>(x, W1, b1, ai, aj);
    pair_kernel<<<BB * NN, 256, 0, stream>>>(ai, aj, W2, b2, out);
}